// Round 5
// baseline (469.893 us; speedup 1.0000x reference)
//
#include <hip/hip_runtime.h>
#include <hip/hip_bf16.h>

#define D_DIM 512
#define H_DIM 512
#define O_DIM 768

using bf16x8 = __attribute__((ext_vector_type(8))) short;
using f32x4  = __attribute__((ext_vector_type(4))) float;

// packed fp32x2 -> bf16x2 (RNE), one VALU inst
static __device__ __forceinline__ unsigned cvtpk(float lo, float hi){
  unsigned r;
  asm("v_cvt_pk_bf16_f32 %0, %1, %2" : "=v"(r) : "v"(lo), "v"(hi));
  return r;
}

static __device__ __forceinline__ float bflo(unsigned u){
  return __uint_as_float(u << 16);
}
static __device__ __forceinline__ float bfhi(unsigned u){
  return __uint_as_float(u & 0xffff0000u);
}

static __device__ __forceinline__ float fast_tanh(float x){
  float e = __expf(2.f * x);         // inf-safe
  return 1.f - 2.f / (e + 1.f);
}

// ordered-uint encoding so atomicMax(unsigned) == float max
static __device__ __forceinline__ unsigned f2ord(float f){
  unsigned u = __float_as_uint(f);
  return (u & 0x80000000u) ? ~u : (u | 0x80000000u);
}
static __device__ __forceinline__ float ord2f(unsigned u){
  u = (u & 0x80000000u) ? (u & 0x7fffffffu) : ~u;
  return __uint_as_float(u);
}

// async global->LDS, 16B per lane, wave-uniform LDS base + lane*16 dest
static __device__ __forceinline__ void gload16(const void* g, void* l){
  __builtin_amdgcn_global_load_lds(
      (const __attribute__((address_space(1))) void*)g,
      (__attribute__((address_space(3))) void*)l, 16, 0, 0);
}

// ---------------------------------------------------------------------------
// fp32 -> bf16 pack (weights only; tiny)
// ---------------------------------------------------------------------------
__global__ void cvt_bf16(const float* __restrict__ in,
                         unsigned short* __restrict__ out, int n8)
{
  int stride = gridDim.x * blockDim.x;
  for (int i = blockIdx.x*blockDim.x + threadIdx.x; i < n8; i += stride){
    const float4* p = (const float4*)in + (size_t)i*2;
    float4 a = p[0], b = p[1];
    uint4 pk;
    pk.x = cvtpk(a.x, a.y);
    pk.y = cvtpk(a.z, a.w);
    pk.z = cvtpk(b.x, b.y);
    pk.w = cvtpk(b.z, b.w);
    ((uint4*)out)[i] = pk;
  }
}

// ---------------------------------------------------------------------------
// GEMM1 (2-phase dbuf): scores = sum_cols tanh(A_f32 @ W1b^T + b1) * w2
// Per K-step: issue next A f32 loads (regs) + next B gload_lds -> buf^1,
// MFMA current buf (setprio), then cvt+ds_write next A, ONE barrier.
// colBase==0 blocks also emit packed bf16 A to Ab. 128x128 tile, BK=64.
// Flat grid + bijective XCD chunked swizzle (N-fast).
// ---------------------------------------------------------------------------
__launch_bounds__(256, 2)
__global__ void gemm1_db(const float* __restrict__ A,
                         const short* __restrict__ Bm,
                         const float* __restrict__ bias,
                         const float* __restrict__ w2,
                         float* __restrict__ out,
                         short* __restrict__ Ab,
                         int M, int nwg)
{
  __shared__ short lds_a[2][128*64];
  __shared__ short lds_b[2][128*64];

  // bijective XCD-chunked swizzle (m204), then N-fast decode
  const int q  = nwg >> 3, rr = nwg & 7;
  const int xcd = blockIdx.x & 7, bidx = blockIdx.x >> 3;
  const int swz = (xcd < rr ? xcd*(q+1) : rr*(q+1) + (xcd-rr)*q) + bidx;
  const int colBase = (swz & 3) * 128;
  const int rowBase = (swz >> 2) * 128;
  const bool writeAb = (colBase == 0);

  const int tid  = threadIdx.x;
  const int lane = tid & 63;
  const int w    = tid >> 6;
  const int wr   = w >> 1, wc = w & 1;
  const int lr   = lane & 15;
  const int lk   = lane >> 4;

  // A staging: 16 rows / 256 threads pass, 16 float4-granules per 256B row
  const int srow = tid >> 4;        // 0..15
  const int sgf  = tid & 15;
  // B staging (gload16): 4 calls x 8 rows per wave
  const int rlocB = lane >> 3;
  const int jB    = lane & 7;

  f32x4 acc[4][4];
  #pragma unroll
  for (int i = 0; i < 4; ++i)
    #pragma unroll
    for (int j = 0; j < 4; ++j)
      acc[i][j] = (f32x4){0.f, 0.f, 0.f, 0.f};

  float4 va[8];

  // ---- prologue: stage K-tile 0 ----
  #pragma unroll
  for (int c = 0; c < 8; ++c){
    int gA = rowBase + c*16 + srow; if (gA > M-1) gA = M-1;
    va[c] = *(const float4*)(A + (size_t)gA*512 + sgf*4);
  }
  #pragma unroll
  for (int c = 0; c < 4; ++c){
    int rt = w*32 + c*8 + rlocB;
    int js = jB ^ (rt & 7);
    gload16(Bm + (size_t)(colBase + rt)*512 + js*8, &lds_b[0][(w*32 + c*8)*64]);
  }
  #pragma unroll
  for (int c = 0; c < 8; ++c){
    int rt = c*16 + srow;
    uint2 pk = { cvtpk(va[c].x, va[c].y), cvtpk(va[c].z, va[c].w) };
    int sidx = (rt*64 + sgf*4) ^ ((rt & 7) << 3);
    *(uint2*)&lds_a[0][sidx] = pk;
    if (writeAb){
      int gA = rowBase + rt;
      if (gA < M) *(uint2*)(Ab + (size_t)gA*512 + sgf*4) = pk;
    }
  }
  __syncthreads();   // drains vmcnt(0): lds_b[0] ready

  int cur = 0;
  for (int kt = 0; kt < 8; ++kt){
    const int nxt = cur ^ 1;
    const int kNext = (kt + 1) * 64;
    if (kt < 7){
      // issue-early: next A tile to regs (A loads FIRST so their vmcnt
      // wait doesn't include the B gloads issued after)
      #pragma unroll
      for (int c = 0; c < 8; ++c){
        int gA = rowBase + c*16 + srow; if (gA > M-1) gA = M-1;
        va[c] = *(const float4*)(A + (size_t)gA*512 + kNext + sgf*4);
      }
      // next B direct to LDS buf^1
      #pragma unroll
      for (int c = 0; c < 4; ++c){
        int rt = w*32 + c*8 + rlocB;
        int js = jB ^ (rt & 7);
        gload16(Bm + (size_t)(colBase + rt)*512 + kNext + js*8,
                &lds_b[nxt][(w*32 + c*8)*64]);
      }
    }
    // compute current buffer
    #pragma unroll
    for (int kk = 0; kk < 2; ++kk){
      bf16x8 af[4], bfr[4];
      #pragma unroll
      for (int mf = 0; mf < 4; ++mf){
        int r   = wr*64 + mf*16 + lr;
        int idx = (r*64 + kk*32 + lk*8) ^ ((r & 7) << 3);
        af[mf] = *(bf16x8*)&lds_a[cur][idx];
      }
      #pragma unroll
      for (int nf = 0; nf < 4; ++nf){
        int r   = wc*64 + nf*16 + lr;
        int idx = (r*64 + kk*32 + lk*8) ^ ((r & 7) << 3);
        bfr[nf] = *(bf16x8*)&lds_b[cur][idx];
      }
      __builtin_amdgcn_s_setprio(1);
      #pragma unroll
      for (int mf = 0; mf < 4; ++mf)
        #pragma unroll
        for (int nf = 0; nf < 4; ++nf)
          acc[mf][nf] = __builtin_amdgcn_mfma_f32_16x16x32_bf16(
              af[mf], bfr[nf], acc[mf][nf], 0, 0, 0);
      __builtin_amdgcn_s_setprio(0);
    }
    if (kt < 7){
      // write-late: cvt + ds_write next A into buf^1 (+ bf16 A copy)
      #pragma unroll
      for (int c = 0; c < 8; ++c){
        int rt = c*16 + srow;
        uint2 pk = { cvtpk(va[c].x, va[c].y), cvtpk(va[c].z, va[c].w) };
        int sidx = (rt*64 + sgf*4) ^ ((rt & 7) << 3);
        *(uint2*)&lds_a[nxt][sidx] = pk;
        if (writeAb){
          int gA = rowBase + rt;
          if (gA < M) *(uint2*)(Ab + (size_t)gA*512 + kNext + sgf*4) = pk;
        }
      }
    }
    __syncthreads();   // one barrier/K-step; drains vmcnt -> lds_b[nxt] ready
    cur = nxt;
  }

  // scores epilogue: tanh + dot w2, reduce over 16 col-lanes, atomicAdd
  #pragma unroll
  for (int mf = 0; mf < 4; ++mf){
    float part[4] = {0.f,0.f,0.f,0.f};
    #pragma unroll
    for (int nf = 0; nf < 4; ++nf){
      int gc = colBase + wc*64 + nf*16 + lr;
      float b = bias[gc], wv = w2[gc];
      #pragma unroll
      for (int r = 0; r < 4; ++r)
        part[r] += fast_tanh(acc[mf][nf][r] + b) * wv;
    }
    #pragma unroll
    for (int r = 0; r < 4; ++r){
      part[r] += __shfl_xor(part[r], 1);
      part[r] += __shfl_xor(part[r], 2);
      part[r] += __shfl_xor(part[r], 4);
      part[r] += __shfl_xor(part[r], 8);
    }
    if (lr == 0){
      int gr = rowBase + wr*64 + mf*16 + lk*4;
      #pragma unroll
      for (int r = 0; r < 4; ++r)
        if (gr + r < M) atomicAdd(&out[gr + r], part[r]);
    }
  }
}

// ---------------------------------------------------------------------------
// GEMM2 (pure bf16, m97 structure): out[M,outStride] = A @ Bm^T + bias
// ---------------------------------------------------------------------------
__launch_bounds__(256, 2)
__global__ void gemm2_bf16(const short* __restrict__ A,
                           const short* __restrict__ Bm,
                           const float* __restrict__ bias,
                           float* __restrict__ out,
                           int M, int outStride)
{
  __shared__ short lds_a[128*64];
  __shared__ short lds_b[128*64];

  const int tid  = threadIdx.x;
  const int lane = tid & 63;
  const int w    = tid >> 6;
  const int wr   = w >> 1, wc = w & 1;
  const int lr   = lane & 15;
  const int lk   = lane >> 4;

  const int colBase = blockIdx.x * 128;
  const int rowBase = blockIdx.y * 128;

  f32x4 acc[4][4];
  #pragma unroll
  for (int i = 0; i < 4; ++i)
    #pragma unroll
    for (int j = 0; j < 4; ++j)
      acc[i][j] = (f32x4){0.f, 0.f, 0.f, 0.f};

  const int subrow = lane >> 3;
  const int gpre   = lane & 7;

  for (int kt = 0; kt < 512/64; ++kt){
    const int kOff = kt * 64;
    #pragma unroll
    for (int c = 0; c < 4; ++c){
      int r    = w*32 + c*8 + subrow;
      int gran = gpre ^ (r & 7);
      int gA   = rowBase + r; if (gA > M-1) gA = M-1;
      gload16(A  + (size_t)gA*512 + kOff + gran*8, &lds_a[(w*32 + c*8)*64]);
      int gB   = colBase + r;
      gload16(Bm + (size_t)gB*512 + kOff + gran*8, &lds_b[(w*32 + c*8)*64]);
    }
    __syncthreads();
    #pragma unroll
    for (int kk = 0; kk < 2; ++kk){
      bf16x8 af[4], bfr[4];
      #pragma unroll
      for (int mf = 0; mf < 4; ++mf){
        int r   = wr*64 + mf*16 + lr;
        int idx = (r*64 + kk*32 + lk*8) ^ ((r & 7) << 3);
        af[mf] = *(bf16x8*)&lds_a[idx];
      }
      #pragma unroll
      for (int nf = 0; nf < 4; ++nf){
        int r   = wc*64 + nf*16 + lr;
        int idx = (r*64 + kk*32 + lk*8) ^ ((r & 7) << 3);
        bfr[nf] = *(bf16x8*)&lds_b[idx];
      }
      #pragma unroll
      for (int mf = 0; mf < 4; ++mf)
        #pragma unroll
        for (int nf = 0; nf < 4; ++nf)
          acc[mf][nf] = __builtin_amdgcn_mfma_f32_16x16x32_bf16(
              af[mf], bfr[nf], acc[mf][nf], 0, 0, 0);
    }
    __syncthreads();
  }

  #pragma unroll
  for (int mf = 0; mf < 4; ++mf){
    int gr = rowBase + wr*64 + mf*16 + lk*4;
    #pragma unroll
    for (int nf = 0; nf < 4; ++nf){
      int gc = colBase + wc*64 + nf*16 + lr;
      float b = bias[gc];
      #pragma unroll
      for (int r = 0; r < 4; ++r)
        if (gr + r < M) out[(size_t)(gr + r)*outStride + gc] = acc[mf][nf][r] + b;
    }
  }
}

// ---------------------------------------------------------------------------
__global__ void edge_pass1(const int* __restrict__ edge, int E,
                           const float* __restrict__ scores,
                           unsigned* __restrict__ smax_o,
                           int* __restrict__ hist)
{
  int e = blockIdx.x*256 + threadIdx.x;
  if (e >= E) return;
  int p = edge[e], l = edge[E + e];
  atomicMax(&smax_o[p], f2ord(scores[l]));
  atomicAdd(&hist[p], 1);
}

__global__ void scan_kernel(const int* __restrict__ hist,
                            int* __restrict__ offsets, int P)
{
  __shared__ int s[1024];
  int t = threadIdx.x;
  int local[16]; int sum = 0;
  #pragma unroll
  for (int i = 0; i < 16; ++i){
    int idx = t*16 + i;
    local[i] = (idx < P) ? hist[idx] : 0;
    sum += local[i];
  }
  s[t] = sum;
  __syncthreads();
  for (int off = 1; off < 1024; off <<= 1){
    int v = (t >= off) ? s[t - off] : 0;
    __syncthreads();
    s[t] += v;
    __syncthreads();
  }
  int run = s[t] - sum;             // exclusive prefix
  #pragma unroll
  for (int i = 0; i < 16; ++i){
    int idx = t*16 + i;
    if (idx < P) offsets[idx] = run;
    run += local[i];
  }
}

__global__ void edge_pass2(const int* __restrict__ edge, int E,
                           const float* __restrict__ scores,
                           const unsigned* __restrict__ smax_o,
                           float* __restrict__ ex,
                           float* __restrict__ esum,
                           const int* __restrict__ offsets,
                           int* __restrict__ cursor,
                           int* __restrict__ sorted)
{
  int e = blockIdx.x*256 + threadIdx.x;
  if (e >= E) return;
  int p = edge[e], l = edge[E + e];
  float v = __expf(scores[l] - ord2f(smax_o[p]));
  ex[e] = v;
  atomicAdd(&esum[p], v);
  int pos = atomicAdd(&cursor[p], 1);
  sorted[offsets[p] + pos] = e;
}

// one WAVE per patient (4/block), bf16 gather with 1-ahead prefetch
__global__ void agg_kernel(const int* __restrict__ edge, int E,
                           const short* __restrict__ Ab,
                           const float* __restrict__ ex,
                           const float* __restrict__ esum,
                           const int* __restrict__ offsets,
                           const int* __restrict__ hist,
                           const int* __restrict__ sorted,
                           unsigned* __restrict__ aggb)
{
  int p    = blockIdx.x*4 + (threadIdx.x >> 6);
  int lane = threadIdx.x & 63;
  int n = hist[p];
  if (n == 0) return;               // row stays zero (memset)
  int start = offsets[p];
  float inv = 1.f / fmaxf(esum[p], 1e-12f);
  float a[8] = {0.f,0.f,0.f,0.f,0.f,0.f,0.f,0.f};
  int e0 = sorted[start];
  uint4 u = *(const uint4*)(Ab + (size_t)edge[E + e0]*512 + lane*8);
  float alpha = ex[e0] * inv;
  for (int i = 0; i < n; ++i){
    uint4 uc = u; float ac = alpha;
    if (i + 1 < n){
      int e2 = sorted[start + i + 1];
      u = *(const uint4*)(Ab + (size_t)edge[E + e2]*512 + lane*8);
      alpha = ex[e2] * inv;
    }
    a[0] += ac * bflo(uc.x);  a[1] += ac * bfhi(uc.x);
    a[2] += ac * bflo(uc.y);  a[3] += ac * bfhi(uc.y);
    a[4] += ac * bflo(uc.z);  a[5] += ac * bfhi(uc.z);
    a[6] += ac * bflo(uc.w);  a[7] += ac * bfhi(uc.w);
  }
  uint4 o = { cvtpk(a[0],a[1]), cvtpk(a[2],a[3]),
              cvtpk(a[4],a[5]), cvtpk(a[6],a[7]) };
  *(uint4*)&aggb[(size_t)p*256 + lane*4] = o;
}

// in-place LayerNorm over rows of 768 in d_out
__global__ void ln_kernel(float* __restrict__ out,
                          const float* __restrict__ gamma,
                          const float* __restrict__ beta)
{
  __shared__ float red1[4];
  __shared__ float red2[4];
  int p = blockIdx.x;
  float* row = out + (size_t)p*768;
  int t = threadIdx.x;
  float v0 = row[t], v1 = row[t+256], v2 = row[t+512];
  float s = v0 + v1 + v2;
  #pragma unroll
  for (int off = 32; off; off >>= 1) s += __shfl_down(s, off);
  int lane = t & 63, wv = t >> 6;
  if (lane == 0) red1[wv] = s;
  __syncthreads();
  float mean = (red1[0]+red1[1]+red1[2]+red1[3]) * (1.f/768.f);
  float d0 = v0-mean, d1 = v1-mean, d2 = v2-mean;
  float qq = d0*d0 + d1*d1 + d2*d2;
  #pragma unroll
  for (int off = 32; off; off >>= 1) qq += __shfl_down(qq, off);
  if (lane == 0) red2[wv] = qq;
  __syncthreads();
  float var = (red2[0]+red2[1]+red2[2]+red2[3]) * (1.f/768.f);
  float inv = rsqrtf(var + 1e-5f);
  row[t]     = d0*inv*gamma[t]     + beta[t];
  row[t+256] = d1*inv*gamma[t+256] + beta[t+256];
  row[t+512] = d2*inv*gamma[t+512] + beta[t+512];
}

// ---------------------------------------------------------------------------
extern "C" void kernel_launch(void* const* d_in, const int* in_sizes, int n_in,
                              void* d_out, int out_size, void* d_ws, size_t ws_size,
                              hipStream_t stream)
{
  const float* lesion_x = (const float*)d_in[0];
  const int*   edge     = (const int*)d_in[1];
  const float* W1    = (const float*)d_in[3];
  const float* b1    = (const float*)d_in[4];
  const float* W2    = (const float*)d_in[5];
  // d_in[6] = b2 — uniform shift, cancels in softmax
  const float* Wp    = (const float*)d_in[7];
  const float* bp    = (const float*)d_in[8];
  const float* gamma = (const float*)d_in[9];
  const float* beta  = (const float*)d_in[10];

  const int L = in_sizes[0] / D_DIM;
  const int E = in_sizes[1] / 2;
  const int P = out_size / O_DIM;

  auto al = [](size_t x){ return (x + 255) & ~(size_t)255; };
  char* ws = (char*)d_ws;
  size_t oScores = 0;
  size_t oSmax   = oScores + al((size_t)L*4);
  size_t oEsum   = oSmax   + al((size_t)P*4);
  size_t oHist   = oEsum   + al((size_t)P*4);
  size_t oCursor = oHist   + al((size_t)P*4);
  size_t smallEnd= oCursor + al((size_t)P*4);
  size_t oAggB   = smallEnd;                        // P*512*2 bf16
  size_t aggEnd  = oAggB   + al((size_t)P*D_DIM*2);
  size_t oOff    = aggEnd;
  size_t oEx     = oOff    + al((size_t)P*4);
  size_t oSorted = oEx     + al((size_t)E*4);
  size_t oW1b    = oSorted + al((size_t)E*4);
  size_t oWpb    = oW1b    + al((size_t)H_DIM*D_DIM*2);
  size_t oAb     = oWpb    + al((size_t)O_DIM*D_DIM*2);
  size_t need    = oAb     + al((size_t)L*D_DIM*2);
  (void)need; // ~230 MB; harness ws is ~1.6 GB

  float*    scores = (float*)(ws + oScores);
  unsigned* smax_o = (unsigned*)(ws + oSmax);
  float*    esum   = (float*)(ws + oEsum);
  int*      hist   = (int*)(ws + oHist);
  int*      cursor = (int*)(ws + oCursor);
  unsigned* aggb   = (unsigned*)(ws + oAggB);
  int*      offs   = (int*)(ws + oOff);
  float*    ex     = (float*)(ws + oEx);
  int*      sorted = (int*)(ws + oSorted);
  short*    W1b    = (short*)(ws + oW1b);
  short*    Wpb    = (short*)(ws + oWpb);
  short*    Ab     = (short*)(ws + oAb);

  hipMemsetAsync(d_ws, 0, smallEnd, stream);
  hipMemsetAsync(ws + oAggB, 0, (size_t)P*D_DIM*2, stream);

  dim3 b256(256);
  int eb = (E + 255) / 256;

  // weight conversions (tiny, BW-bound)
  cvt_bf16<<<128, b256, 0, stream>>>(W1, (unsigned short*)W1b, H_DIM*D_DIM/8);
  cvt_bf16<<<192, b256, 0, stream>>>(Wp, (unsigned short*)Wpb, O_DIM*D_DIM/8);

  // GEMM1: 2-phase dbuf, fp32 A reg-staged -> bf16 LDS; emits bf16 Ab
  int nRow = (L + 127) / 128;
  int nwg  = 4 * nRow;
  gemm1_db<<<nwg, b256, 0, stream>>>(lesion_x, W1b, b1, W2, scores, Ab, L, nwg);

  edge_pass1<<<eb, b256, 0, stream>>>(edge, E, scores, smax_o, hist);
  scan_kernel<<<1, 1024, 0, stream>>>(hist, offs, P);
  edge_pass2<<<eb, b256, 0, stream>>>(edge, E, scores, smax_o, ex, esum,
                                      offs, cursor, sorted);
  agg_kernel<<<P/4, b256, 0, stream>>>(edge, E, Ab, ex, esum, offs,
                                       hist, sorted, aggb);
  gemm2_bf16<<<dim3(O_DIM/128, P/128), b256, 0, stream>>>(
      (const short*)aggb, Wpb, bp, (float*)d_out, P, O_DIM);
  ln_kernel<<<P, b256, 0, stream>>>((float*)d_out, gamma, beta);
}

// Round 6
// 439.184 us; speedup vs baseline: 1.0699x; 1.0699x over previous
//
#include <hip/hip_runtime.h>
#include <hip/hip_bf16.h>

#define D_DIM 512
#define H_DIM 512
#define O_DIM 768

using bf16x8 = __attribute__((ext_vector_type(8))) short;
using f32x4  = __attribute__((ext_vector_type(4))) float;

// packed fp32x2 -> bf16x2 (RNE), one VALU inst
static __device__ __forceinline__ unsigned cvtpk(float lo, float hi){
  unsigned r;
  asm("v_cvt_pk_bf16_f32 %0, %1, %2" : "=v"(r) : "v"(lo), "v"(hi));
  return r;
}

static __device__ __forceinline__ float bflo(unsigned u){
  return __uint_as_float(u << 16);
}
static __device__ __forceinline__ float bfhi(unsigned u){
  return __uint_as_float(u & 0xffff0000u);
}

static __device__ __forceinline__ float fast_tanh(float x){
  float e = __expf(2.f * x);         // inf-safe
  return 1.f - 2.f / (e + 1.f);
}

// ordered-uint encoding so atomicMax(unsigned) == float max
static __device__ __forceinline__ unsigned f2ord(float f){
  unsigned u = __float_as_uint(f);
  return (u & 0x80000000u) ? ~u : (u | 0x80000000u);
}
static __device__ __forceinline__ float ord2f(unsigned u){
  u = (u & 0x80000000u) ? (u & 0x7fffffffu) : ~u;
  return __uint_as_float(u);
}

// async global->LDS, 16B per lane, wave-uniform LDS base + lane*16 dest
static __device__ __forceinline__ void gload16(const void* g, void* l){
  __builtin_amdgcn_global_load_lds(
      (const __attribute__((address_space(1))) void*)g,
      (__attribute__((address_space(3))) void*)l, 16, 0, 0);
}

// ---------------------------------------------------------------------------
// fp32 -> bf16 pack (weights only; tiny)
// ---------------------------------------------------------------------------
__global__ void cvt_bf16(const float* __restrict__ in,
                         unsigned short* __restrict__ out, int n8)
{
  int stride = gridDim.x * blockDim.x;
  for (int i = blockIdx.x*blockDim.x + threadIdx.x; i < n8; i += stride){
    const float4* p = (const float4*)in + (size_t)i*2;
    float4 a = p[0], b = p[1];
    uint4 pk;
    pk.x = cvtpk(a.x, a.y);
    pk.y = cvtpk(a.z, a.w);
    pk.z = cvtpk(b.x, b.y);
    pk.w = cvtpk(b.z, b.w);
    ((uint4*)out)[i] = pk;
  }
}

// ---------------------------------------------------------------------------
// GEMM1 (wide tile): scores = sum_cols tanh(A_f32 @ W1b^T + b1) * w2
// Tile 128(M) x 256(N), BK=64, 4 waves (2x2), per-wave 64x128 = 4x8 frags.
// Single-buffer LDS (48KB), R4's 2-barrier loop: A f32 reg-stage ->
// cvt_pk -> swizzled ds_write; B bf16 via global_load_lds. 64 MFMA /
// K-step / wave (2x R4) at identical A-staging cost.
// colBase==0 blocks also emit packed bf16 A to Ab.
// Flat grid + bijective XCD chunked swizzle (N-fast).
// ---------------------------------------------------------------------------
__launch_bounds__(256, 2)
__global__ void gemm1_wide(const float* __restrict__ A,
                           const short* __restrict__ Bm,
                           const float* __restrict__ bias,
                           const float* __restrict__ w2,
                           float* __restrict__ out,
                           short* __restrict__ Ab,
                           int M, int nwg)
{
  __shared__ short lds_a[128*64];    // 16 KB
  __shared__ short lds_b[256*64];    // 32 KB

  // bijective XCD-chunked swizzle (m204), then N-fast decode (2 col blocks)
  const int q  = nwg >> 3, rr = nwg & 7;
  const int xcd = blockIdx.x & 7, bidx = blockIdx.x >> 3;
  const int swz = (xcd < rr ? xcd*(q+1) : rr*(q+1) + (xcd-rr)*q) + bidx;
  const int colBase = (swz & 1) * 256;
  const int rowBase = (swz >> 1) * 128;
  const bool writeAb = (colBase == 0);

  const int tid  = threadIdx.x;
  const int lane = tid & 63;
  const int w    = tid >> 6;
  const int wr   = w >> 1, wc = w & 1;   // wave grid: 2(M) x 2(N)
  const int lr   = lane & 15;
  const int lk   = lane >> 4;

  // A staging: 16 rows / pass, 16 float4-granules per 256B fp32 row
  const int srow = tid >> 4;        // 0..15
  const int sgf  = tid & 15;
  // B staging (gload16): 8 calls x 8 rows per wave (wave covers 64 rows)
  const int rlocB = lane >> 3;
  const int jB    = lane & 7;

  f32x4 acc[4][8];
  #pragma unroll
  for (int i = 0; i < 4; ++i)
    #pragma unroll
    for (int j = 0; j < 8; ++j)
      acc[i][j] = (f32x4){0.f, 0.f, 0.f, 0.f};

  for (int kt = 0; kt < 512/64; ++kt){
    const int kOff = kt * 64;
    // A: coalesced fp32 loads first (their vmcnt wait excludes B gloads)
    float4 va[8];
    #pragma unroll
    for (int c = 0; c < 8; ++c){
      int gA = rowBase + c*16 + srow; if (gA > M-1) gA = M-1;
      va[c] = *(const float4*)(A + (size_t)gA*512 + kOff + sgf*4);
    }
    // B async direct-to-LDS: 256 rows, wave w stages rows [w*64, w*64+64)
    #pragma unroll
    for (int c = 0; c < 8; ++c){
      int rt = w*64 + c*8 + rlocB;
      int js = jB ^ (rt & 7);
      gload16(Bm + (size_t)(colBase + rt)*512 + kOff + js*8,
              &lds_b[(w*64 + c*8)*64]);
    }
    // cvt + swizzled ds_write A (+ bf16 A copy)
    #pragma unroll
    for (int c = 0; c < 8; ++c){
      int rt = c*16 + srow;
      uint2 pk = { cvtpk(va[c].x, va[c].y), cvtpk(va[c].z, va[c].w) };
      int sidx = (rt*64 + sgf*4) ^ ((rt & 7) << 3);
      *(uint2*)&lds_a[sidx] = pk;
      if (writeAb){
        int gA = rowBase + rt;
        if (gA < M) *(uint2*)(Ab + (size_t)gA*512 + kOff + sgf*4) = pk;
      }
    }
    __syncthreads();   // drains vmcnt: lds_b ready; lds_a writes visible
    #pragma unroll
    for (int kk = 0; kk < 2; ++kk){
      bf16x8 af[4], bfr[8];
      #pragma unroll
      for (int mf = 0; mf < 4; ++mf){
        int r   = wr*64 + mf*16 + lr;
        int idx = (r*64 + kk*32 + lk*8) ^ ((r & 7) << 3);
        af[mf] = *(bf16x8*)&lds_a[idx];
      }
      #pragma unroll
      for (int nf = 0; nf < 8; ++nf){
        int r   = wc*128 + nf*16 + lr;
        int idx = (r*64 + kk*32 + lk*8) ^ ((r & 7) << 3);
        bfr[nf] = *(bf16x8*)&lds_b[idx];
      }
      __builtin_amdgcn_s_setprio(1);
      #pragma unroll
      for (int mf = 0; mf < 4; ++mf)
        #pragma unroll
        for (int nf = 0; nf < 8; ++nf)
          acc[mf][nf] = __builtin_amdgcn_mfma_f32_16x16x32_bf16(
              af[mf], bfr[nf], acc[mf][nf], 0, 0, 0);
      __builtin_amdgcn_s_setprio(0);
    }
    __syncthreads();
  }

  // scores epilogue: tanh + dot w2, reduce over 16 col-lanes, atomicAdd
  #pragma unroll
  for (int mf = 0; mf < 4; ++mf){
    float part[4] = {0.f,0.f,0.f,0.f};
    #pragma unroll
    for (int nf = 0; nf < 8; ++nf){
      int gc = colBase + wc*128 + nf*16 + lr;
      float b = bias[gc], wv = w2[gc];
      #pragma unroll
      for (int r = 0; r < 4; ++r)
        part[r] += fast_tanh(acc[mf][nf][r] + b) * wv;
    }
    #pragma unroll
    for (int r = 0; r < 4; ++r){
      part[r] += __shfl_xor(part[r], 1);
      part[r] += __shfl_xor(part[r], 2);
      part[r] += __shfl_xor(part[r], 4);
      part[r] += __shfl_xor(part[r], 8);
    }
    if (lr == 0){
      int gr = rowBase + wr*64 + mf*16 + lk*4;
      #pragma unroll
      for (int r = 0; r < 4; ++r)
        if (gr + r < M) atomicAdd(&out[gr + r], part[r]);
    }
  }
}

// ---------------------------------------------------------------------------
// GEMM2 (pure bf16, m97 structure): out[M,outStride] = A @ Bm^T + bias
// ---------------------------------------------------------------------------
__launch_bounds__(256, 2)
__global__ void gemm2_bf16(const short* __restrict__ A,
                           const short* __restrict__ Bm,
                           const float* __restrict__ bias,
                           float* __restrict__ out,
                           int M, int outStride)
{
  __shared__ short lds_a[128*64];
  __shared__ short lds_b[128*64];

  const int tid  = threadIdx.x;
  const int lane = tid & 63;
  const int w    = tid >> 6;
  const int wr   = w >> 1, wc = w & 1;
  const int lr   = lane & 15;
  const int lk   = lane >> 4;

  const int colBase = blockIdx.x * 128;
  const int rowBase = blockIdx.y * 128;

  f32x4 acc[4][4];
  #pragma unroll
  for (int i = 0; i < 4; ++i)
    #pragma unroll
    for (int j = 0; j < 4; ++j)
      acc[i][j] = (f32x4){0.f, 0.f, 0.f, 0.f};

  const int subrow = lane >> 3;
  const int gpre   = lane & 7;

  for (int kt = 0; kt < 512/64; ++kt){
    const int kOff = kt * 64;
    #pragma unroll
    for (int c = 0; c < 4; ++c){
      int r    = w*32 + c*8 + subrow;
      int gran = gpre ^ (r & 7);
      int gA   = rowBase + r; if (gA > M-1) gA = M-1;
      gload16(A  + (size_t)gA*512 + kOff + gran*8, &lds_a[(w*32 + c*8)*64]);
      int gB   = colBase + r;
      gload16(Bm + (size_t)gB*512 + kOff + gran*8, &lds_b[(w*32 + c*8)*64]);
    }
    __syncthreads();
    #pragma unroll
    for (int kk = 0; kk < 2; ++kk){
      bf16x8 af[4], bfr[4];
      #pragma unroll
      for (int mf = 0; mf < 4; ++mf){
        int r   = wr*64 + mf*16 + lr;
        int idx = (r*64 + kk*32 + lk*8) ^ ((r & 7) << 3);
        af[mf] = *(bf16x8*)&lds_a[idx];
      }
      #pragma unroll
      for (int nf = 0; nf < 4; ++nf){
        int r   = wc*64 + nf*16 + lr;
        int idx = (r*64 + kk*32 + lk*8) ^ ((r & 7) << 3);
        bfr[nf] = *(bf16x8*)&lds_b[idx];
      }
      #pragma unroll
      for (int mf = 0; mf < 4; ++mf)
        #pragma unroll
        for (int nf = 0; nf < 4; ++nf)
          acc[mf][nf] = __builtin_amdgcn_mfma_f32_16x16x32_bf16(
              af[mf], bfr[nf], acc[mf][nf], 0, 0, 0);
    }
    __syncthreads();
  }

  #pragma unroll
  for (int mf = 0; mf < 4; ++mf){
    int gr = rowBase + wr*64 + mf*16 + lk*4;
    #pragma unroll
    for (int nf = 0; nf < 4; ++nf){
      int gc = colBase + wc*64 + nf*16 + lr;
      float b = bias[gc];
      #pragma unroll
      for (int r = 0; r < 4; ++r)
        if (gr + r < M) out[(size_t)(gr + r)*outStride + gc] = acc[mf][nf][r] + b;
    }
  }
}

// ---------------------------------------------------------------------------
__global__ void edge_pass1(const int* __restrict__ edge, int E,
                           const float* __restrict__ scores,
                           unsigned* __restrict__ smax_o,
                           int* __restrict__ hist)
{
  int e = blockIdx.x*256 + threadIdx.x;
  if (e >= E) return;
  int p = edge[e], l = edge[E + e];
  atomicMax(&smax_o[p], f2ord(scores[l]));
  atomicAdd(&hist[p], 1);
}

__global__ void scan_kernel(const int* __restrict__ hist,
                            int* __restrict__ offsets, int P)
{
  __shared__ int s[1024];
  int t = threadIdx.x;
  int local[16]; int sum = 0;
  #pragma unroll
  for (int i = 0; i < 16; ++i){
    int idx = t*16 + i;
    local[i] = (idx < P) ? hist[idx] : 0;
    sum += local[i];
  }
  s[t] = sum;
  __syncthreads();
  for (int off = 1; off < 1024; off <<= 1){
    int v = (t >= off) ? s[t - off] : 0;
    __syncthreads();
    s[t] += v;
    __syncthreads();
  }
  int run = s[t] - sum;             // exclusive prefix
  #pragma unroll
  for (int i = 0; i < 16; ++i){
    int idx = t*16 + i;
    if (idx < P) offsets[idx] = run;
    run += local[i];
  }
}

__global__ void edge_pass2(const int* __restrict__ edge, int E,
                           const float* __restrict__ scores,
                           const unsigned* __restrict__ smax_o,
                           float* __restrict__ ex,
                           float* __restrict__ esum,
                           const int* __restrict__ offsets,
                           int* __restrict__ cursor,
                           int* __restrict__ sorted)
{
  int e = blockIdx.x*256 + threadIdx.x;
  if (e >= E) return;
  int p = edge[e], l = edge[E + e];
  float v = __expf(scores[l] - ord2f(smax_o[p]));
  ex[e] = v;
  atomicAdd(&esum[p], v);
  int pos = atomicAdd(&cursor[p], 1);
  sorted[offsets[p] + pos] = e;
}

// one WAVE per patient (4/block), bf16 gather with 1-ahead prefetch
__global__ void agg_kernel(const int* __restrict__ edge, int E,
                           const short* __restrict__ Ab,
                           const float* __restrict__ ex,
                           const float* __restrict__ esum,
                           const int* __restrict__ offsets,
                           const int* __restrict__ hist,
                           const int* __restrict__ sorted,
                           unsigned* __restrict__ aggb)
{
  int p    = blockIdx.x*4 + (threadIdx.x >> 6);
  int lane = threadIdx.x & 63;
  int n = hist[p];
  if (n == 0) return;               // row stays zero (memset)
  int start = offsets[p];
  float inv = 1.f / fmaxf(esum[p], 1e-12f);
  float a[8] = {0.f,0.f,0.f,0.f,0.f,0.f,0.f,0.f};
  int e0 = sorted[start];
  uint4 u = *(const uint4*)(Ab + (size_t)edge[E + e0]*512 + lane*8);
  float alpha = ex[e0] * inv;
  for (int i = 0; i < n; ++i){
    uint4 uc = u; float ac = alpha;
    if (i + 1 < n){
      int e2 = sorted[start + i + 1];
      u = *(const uint4*)(Ab + (size_t)edge[E + e2]*512 + lane*8);
      alpha = ex[e2] * inv;
    }
    a[0] += ac * bflo(uc.x);  a[1] += ac * bfhi(uc.x);
    a[2] += ac * bflo(uc.y);  a[3] += ac * bfhi(uc.y);
    a[4] += ac * bflo(uc.z);  a[5] += ac * bfhi(uc.z);
    a[6] += ac * bflo(uc.w);  a[7] += ac * bfhi(uc.w);
  }
  uint4 o = { cvtpk(a[0],a[1]), cvtpk(a[2],a[3]),
              cvtpk(a[4],a[5]), cvtpk(a[6],a[7]) };
  *(uint4*)&aggb[(size_t)p*256 + lane*4] = o;
}

// in-place LayerNorm over rows of 768 in d_out
__global__ void ln_kernel(float* __restrict__ out,
                          const float* __restrict__ gamma,
                          const float* __restrict__ beta)
{
  __shared__ float red1[4];
  __shared__ float red2[4];
  int p = blockIdx.x;
  float* row = out + (size_t)p*768;
  int t = threadIdx.x;
  float v0 = row[t], v1 = row[t+256], v2 = row[t+512];
  float s = v0 + v1 + v2;
  #pragma unroll
  for (int off = 32; off; off >>= 1) s += __shfl_down(s, off);
  int lane = t & 63, wv = t >> 6;
  if (lane == 0) red1[wv] = s;
  __syncthreads();
  float mean = (red1[0]+red1[1]+red1[2]+red1[3]) * (1.f/768.f);
  float d0 = v0-mean, d1 = v1-mean, d2 = v2-mean;
  float qq = d0*d0 + d1*d1 + d2*d2;
  #pragma unroll
  for (int off = 32; off; off >>= 1) qq += __shfl_down(qq, off);
  if (lane == 0) red2[wv] = qq;
  __syncthreads();
  float var = (red2[0]+red2[1]+red2[2]+red2[3]) * (1.f/768.f);
  float inv = rsqrtf(var + 1e-5f);
  row[t]     = d0*inv*gamma[t]     + beta[t];
  row[t+256] = d1*inv*gamma[t+256] + beta[t+256];
  row[t+512] = d2*inv*gamma[t+512] + beta[t+512];
}

// ---------------------------------------------------------------------------
extern "C" void kernel_launch(void* const* d_in, const int* in_sizes, int n_in,
                              void* d_out, int out_size, void* d_ws, size_t ws_size,
                              hipStream_t stream)
{
  const float* lesion_x = (const float*)d_in[0];
  const int*   edge     = (const int*)d_in[1];
  const float* W1    = (const float*)d_in[3];
  const float* b1    = (const float*)d_in[4];
  const float* W2    = (const float*)d_in[5];
  // d_in[6] = b2 — uniform shift, cancels in softmax
  const float* Wp    = (const float*)d_in[7];
  const float* bp    = (const float*)d_in[8];
  const float* gamma = (const float*)d_in[9];
  const float* beta  = (const float*)d_in[10];

  const int L = in_sizes[0] / D_DIM;
  const int E = in_sizes[1] / 2;
  const int P = out_size / O_DIM;

  auto al = [](size_t x){ return (x + 255) & ~(size_t)255; };
  char* ws = (char*)d_ws;
  size_t oScores = 0;
  size_t oSmax   = oScores + al((size_t)L*4);
  size_t oEsum   = oSmax   + al((size_t)P*4);
  size_t oHist   = oEsum   + al((size_t)P*4);
  size_t oCursor = oHist   + al((size_t)P*4);
  size_t smallEnd= oCursor + al((size_t)P*4);
  size_t oAggB   = smallEnd;                        // P*512*2 bf16
  size_t aggEnd  = oAggB   + al((size_t)P*D_DIM*2);
  size_t oOff    = aggEnd;
  size_t oEx     = oOff    + al((size_t)P*4);
  size_t oSorted = oEx     + al((size_t)E*4);
  size_t oW1b    = oSorted + al((size_t)E*4);
  size_t oWpb    = oW1b    + al((size_t)H_DIM*D_DIM*2);
  size_t oAb     = oWpb    + al((size_t)O_DIM*D_DIM*2);
  size_t need    = oAb     + al((size_t)L*D_DIM*2);
  (void)need; // ~230 MB; harness ws is ~1.6 GB

  float*    scores = (float*)(ws + oScores);
  unsigned* smax_o = (unsigned*)(ws + oSmax);
  float*    esum   = (float*)(ws + oEsum);
  int*      hist   = (int*)(ws + oHist);
  int*      cursor = (int*)(ws + oCursor);
  unsigned* aggb   = (unsigned*)(ws + oAggB);
  int*      offs   = (int*)(ws + oOff);
  float*    ex     = (float*)(ws + oEx);
  int*      sorted = (int*)(ws + oSorted);
  short*    W1b    = (short*)(ws + oW1b);
  short*    Wpb    = (short*)(ws + oWpb);
  short*    Ab     = (short*)(ws + oAb);

  hipMemsetAsync(d_ws, 0, smallEnd, stream);
  hipMemsetAsync(ws + oAggB, 0, (size_t)P*D_DIM*2, stream);

  dim3 b256(256);
  int eb = (E + 255) / 256;

  // weight conversions (tiny, BW-bound)
  cvt_bf16<<<128, b256, 0, stream>>>(W1, (unsigned short*)W1b, H_DIM*D_DIM/8);
  cvt_bf16<<<192, b256, 0, stream>>>(Wp, (unsigned short*)Wpb, O_DIM*D_DIM/8);

  // GEMM1: 128x256 tile, fp32 A reg-staged -> bf16 LDS; emits bf16 Ab
  int nRow = (L + 127) / 128;
  int nwg  = 2 * nRow;
  gemm1_wide<<<nwg, b256, 0, stream>>>(lesion_x, W1b, b1, W2, scores, Ab, L, nwg);

  edge_pass1<<<eb, b256, 0, stream>>>(edge, E, scores, smax_o, hist);
  scan_kernel<<<1, 1024, 0, stream>>>(hist, offs, P);
  edge_pass2<<<eb, b256, 0, stream>>>(edge, E, scores, smax_o, ex, esum,
                                      offs, cursor, sorted);
  agg_kernel<<<P/4, b256, 0, stream>>>(edge, E, Ab, ex, esum, offs,
                                       hist, sorted, aggb);
  gemm2_bf16<<<dim3(O_DIM/128, P/128), b256, 0, stream>>>(
      (const short*)aggb, Wpb, bp, (float*)d_out, P, O_DIM);
  ln_kernel<<<P, b256, 0, stream>>>((float*)d_out, gamma, beta);
}